// Round 8
// baseline (359.890 us; speedup 1.0000x reference)
//
#include <hip/hip_runtime.h>
#include <hip/hip_bf16.h>

typedef short bf16x8 __attribute__((ext_vector_type(8)));   // 8 bf16 bit-patterns (4 VGPRs)
typedef float f32x4 __attribute__((ext_vector_type(4)));

__device__ __forceinline__ float bf2f(__hip_bfloat16 v) { return __bfloat162float(v); }
__device__ __forceinline__ float sh2f(short s) {
    union { float f; unsigned u; } c; c.u = ((unsigned)(unsigned short)s) << 16; return c.f;
}
__device__ __forceinline__ short f2sh(float f) {
    __hip_bfloat16 b = __float2bfloat16(f); return *(short*)&b;
}

__device__ __forceinline__ float loadAny(const void* p, size_t i, int isf32) {
    return isf32 ? ((const float*)p)[i] : bf2f(((const __hip_bfloat16*)p)[i]);
}

// ---------------- fused pre-pass: dtype detect (per-block, wave 0) + ingest x->bf16
//                  + weight prep in MFMA FRAGMENT ORDER + per-edge deg/rank atomics + flag
// Fragment order (verified round 6): elem (n=outcol, k) ->
//   idx = [kt=k>>5][nt=n>>4][lane=((k>>3)&3)*16+(n&15)][k&7]
// deg must be zeroed (hipMemsetAsync) BEFORE this kernel.
__global__ void pre_kernel(const void* __restrict__ x,
                           const void* W1l, const void* W1r, const void* W2l, const void* W2r,
                           const void* b1l, const void* b2l, const void* Wh1, const void* Wh2,
                           const void* bh1, const void* bh2,
                           const int* __restrict__ ei, int E,
                           __hip_bfloat16* __restrict__ xn,
                           __hip_bfloat16* __restrict__ W1f, __hip_bfloat16* __restrict__ W2f,
                           __hip_bfloat16* __restrict__ sb,
                           int* __restrict__ deg, int* __restrict__ rank,
                           int* __restrict__ flag, int N) {
    __shared__ int sflag;
    int tid = threadIdx.x;
    if (tid < 64) {                               // wave 0: local dtype detect (128B of x)
        const unsigned short* xu = (const unsigned short*)x;
        unsigned short u = xu[tid * 2];
        unsigned e = (u >> 7) & 0xFF;
        bool good = (u == 0) || (e >= 110 && e <= 137);
        unsigned long long m = __ballot(good);
        if (tid == 0) sflag = (__popcll(m) < 32) ? 1 : 0;
    }
    __syncthreads();
    int isf32 = sflag;
    int gid = blockIdx.x * 256 + tid;
    if (gid == 0) *flag = isf32;                  // for gemm2 epilogue + heads

    if (gid < E) {                                // CSR pass 1: degree count + edge rank
        rank[gid] = atomicAdd(&deg[ei[E + gid]], 1);
    }

    int n4 = N * 32;
    if (gid < n4) {                               // ingest: 4 elems/thread
        short4 o;
        if (isf32) {
            float4 v = ((const float4*)x)[gid];
            o.x = f2sh(v.x); o.y = f2sh(v.y); o.z = f2sh(v.z); o.w = f2sh(v.w);
        } else {
            o = ((const short4*)x)[gid];
        }
        ((short4*)xn)[gid] = o;
    }

    if (gid < 65536) {                            // W1f: [W1l | W1r], n 0..255, k 0..255
        int n = gid >> 8, k = gid & 255;
        float v = (k < 128) ? loadAny(W1l, n * 128 + k, isf32)
                            : loadAny(W1r, n * 128 + (k - 128), isf32);
        int idx = ((((k >> 5) * 16 + (n >> 4)) * 64) + ((k >> 3) & 3) * 16 + (n & 15)) * 8 + (k & 7);
        W1f[idx] = __float2bfloat16(v);
        return;
    }
    int u = gid - 65536;
    if (u < 131072) {                             // W2f: [W2l | W2r], n 0..255, k 0..511
        int n = u >> 9, k = u & 511;
        float v = (k < 256) ? loadAny(W2l, n * 256 + k, isf32)
                            : loadAny(W2r, n * 256 + (k - 256), isf32);
        int idx = ((((k >> 5) * 16 + (n >> 4)) * 64) + ((k >> 3) & 3) * 16 + (n & 15)) * 8 + (k & 7);
        W2f[idx] = __float2bfloat16(v);
        return;
    }
    int s = u - 131072;
    float v;
    if      (s < 256)  v = loadAny(b1l, s, isf32);
    else if (s < 512)  v = loadAny(b2l, s - 256, isf32);
    else if (s < 1536) v = loadAny(Wh1, s - 512, isf32);
    else if (s < 2304) v = loadAny(Wh2, s - 1536, isf32);
    else if (s < 2308) v = loadAny(bh1, s - 2304, isf32);
    else if (s < 2311) v = loadAny(bh2, s - 2308, isf32);
    else return;
    sb[s] = __float2bfloat16(v);
}

__global__ __launch_bounds__(256) void scanA_kernel(const int* __restrict__ deg,
                                                    int* __restrict__ off,
                                                    int* __restrict__ bsum, int N) {
    __shared__ int ts[256];
    int t = threadIdx.x;
    int base = blockIdx.x * 1024 + t * 4;
    int v0 = (base + 0 < N) ? deg[base + 0] : 0;
    int v1 = (base + 1 < N) ? deg[base + 1] : 0;
    int v2 = (base + 2 < N) ? deg[base + 2] : 0;
    int v3 = (base + 3 < N) ? deg[base + 3] : 0;
    int i0 = v0, i1 = i0 + v1, i2 = i1 + v2, i3 = i2 + v3;
    ts[t] = i3;
    __syncthreads();
    for (int d = 1; d < 256; d <<= 1) {
        int x = (t >= d) ? ts[t - d] : 0;
        __syncthreads();
        ts[t] += x;
        __syncthreads();
    }
    int excl = (t > 0) ? ts[t - 1] : 0;
    if (base + 0 < N) off[base + 1] = excl + i0;
    if (base + 1 < N) off[base + 2] = excl + i1;
    if (base + 2 < N) off[base + 3] = excl + i2;
    if (base + 3 < N) off[base + 4] = excl + i3;
    if (t == 255) bsum[blockIdx.x] = ts[255];
}

// addC with inline scan of bsum (nb <= 64): each block redundantly prefix-scans the
// 49 block totals in wave 0 (shfl_up), then applies the exclusive offset.
__global__ void addC_kernel(int* __restrict__ off, const int* __restrict__ bsum,
                            int N, int nb) {
    __shared__ int ex[64];
    int t = threadIdx.x;
    if (t < 64) {
        int v = (t < nb) ? bsum[t] : 0;
        for (int d = 1; d < 64; d <<= 1) {
            int y = __shfl_up(v, d, 64);
            if (t >= d) v += y;
        }
        ex[t] = v;                                // inclusive scan
    }
    __syncthreads();
    int i = blockIdx.x * 256 + t;
    if (i == 0) off[0] = 0;
    if (i < N) {
        int b = i >> 10;
        int excl = (b > 0) ? ex[b - 1] : 0;
        off[i + 1] += excl;
    }
}

// fill: NO atomics — pos = off[dst] + rank[t]; srcs stored as u16 (N < 65536)
__global__ void fill_kernel(const int* __restrict__ ei, int E,
                            const int* __restrict__ off, const int* __restrict__ rank,
                            unsigned short* __restrict__ srcs) {
    int t = blockIdx.x * blockDim.x + threadIdx.x;
    if (t >= E) return;
    int dst = ei[E + t];
    int pos = off[dst] + rank[t];
    srcs[pos] = (unsigned short)ei[t];
}

// ---------------- gather-mean F=128: 4 nodes/wave (16 lanes x 16B = 256B row), 8-way unroll
__global__ void gather1_kernel(const __hip_bfloat16* __restrict__ x,
                               const int* __restrict__ off,
                               const unsigned short* __restrict__ srcs,
                               __hip_bfloat16* __restrict__ agg, int N) {
    int gid  = blockIdx.x * blockDim.x + threadIdx.x;
    int wid  = gid >> 6;
    int lane = threadIdx.x & 63;
    int node = wid * 4 + (lane >> 4);
    int t    = lane & 15;                         // 16B unit within row (16 units)
    if (node >= N) return;
    int beg = off[node], end = off[node + 1];
    float a[8] = {0.f, 0.f, 0.f, 0.f, 0.f, 0.f, 0.f, 0.f};
    const bf16x8* xb = (const bf16x8*)x;
    int e = beg;
    for (; e + 7 < end; e += 8) {
        bf16x8 v[8];
#pragma unroll
        for (int j = 0; j < 8; j++) v[j] = xb[(size_t)srcs[e + j] * 16 + t];
#pragma unroll
        for (int j = 0; j < 8; j++)
#pragma unroll
            for (int k = 0; k < 8; k++) a[k] += sh2f(v[j][k]);
    }
    for (; e < end; e++) {
        bf16x8 v = xb[(size_t)srcs[e] * 16 + t];
#pragma unroll
        for (int k = 0; k < 8; k++) a[k] += sh2f(v[k]);
    }
    float inv = 1.0f / fmaxf((float)(end - beg), 1.0f);
    bf16x8 o;
#pragma unroll
    for (int k = 0; k < 8; k++) o[k] = f2sh(a[k] * inv);
    ((bf16x8*)agg)[(size_t)node * 16 + t] = o;
}

// ---------------- gather-mean F=256: 2 nodes/wave (32 lanes x 16B = 512B row), 8-way unroll
__global__ void gather2_kernel(const __hip_bfloat16* __restrict__ h,
                               const int* __restrict__ off,
                               const unsigned short* __restrict__ srcs,
                               __hip_bfloat16* __restrict__ agg, int N) {
    int gid  = blockIdx.x * blockDim.x + threadIdx.x;
    int wid  = gid >> 6;
    int lane = threadIdx.x & 63;
    int node = wid * 2 + (lane >> 5);
    int t    = lane & 31;                         // 16B unit within row (32 units)
    if (node >= N) return;
    int beg = off[node], end = off[node + 1];
    float a[8] = {0.f, 0.f, 0.f, 0.f, 0.f, 0.f, 0.f, 0.f};
    const bf16x8* hb = (const bf16x8*)h;
    int e = beg;
    for (; e + 7 < end; e += 8) {
        bf16x8 v[8];
#pragma unroll
        for (int j = 0; j < 8; j++) v[j] = hb[(size_t)srcs[e + j] * 32 + t];
#pragma unroll
        for (int j = 0; j < 8; j++)
#pragma unroll
            for (int k = 0; k < 8; k++) a[k] += sh2f(v[j][k]);
    }
    for (; e < end; e++) {
        bf16x8 v = hb[(size_t)srcs[e] * 32 + t];
#pragma unroll
        for (int k = 0; k < 8; k++) a[k] += sh2f(v[k]);
    }
    float inv = 1.0f / fmaxf((float)(end - beg), 1.0f);
    bf16x8 o;
#pragma unroll
    for (int k = 0; k < 8; k++) o[k] = f2sh(a[k] * inv);
    ((bf16x8*)agg)[(size_t)node * 32 + t] = o;
}

// ---------------- barrier-free GEMM: A direct from global (depth-2 prefetch),
// B fragments direct from pre-swizzled Wf in global (L2-resident, shared by all
// blocks; all 4 waves read the same 16B fragments -> L2 broadcast). No LDS, no
// __syncthreads -> occupancy bounded only by VGPRs.
// Tile: 128 rows x 128 cols per block, 4 waves (each wave 32 rows x 128 cols).
struct AFrag { bf16x8 v[2]; };

template <int K, int KA, bool RELU, bool TOOUT>
__global__ __launch_bounds__(256) void gemm_nolds(const __hip_bfloat16* __restrict__ A1,
                                                  const __hip_bfloat16* __restrict__ A2, int M,
                                                  const short* __restrict__ Wf,
                                                  const __hip_bfloat16* __restrict__ bias,
                                                  __hip_bfloat16* __restrict__ outb,
                                                  void* __restrict__ dout,
                                                  const int* __restrict__ flag) {
    constexpr int KB = K - KA;
    constexpr int KT = K / 32;
    int tid  = threadIdx.x;
    int wave = tid >> 6, lane = tid & 63, quad = lane >> 4, l15 = lane & 15;
    int rowBlk = blockIdx.x >> 1, half = blockIdx.x & 1;
    int R0 = rowBlk * 128;
    int cbase = half * 128;

    int mrow[2];
#pragma unroll
    for (int rt = 0; rt < 2; rt++) mrow[rt] = min(R0 + wave * 32 + rt * 16 + l15, M - 1);

    auto loadA = [&](int kglob) {
        AFrag f;
#pragma unroll
        for (int rt = 0; rt < 2; rt++) {
            const short* ap = (kglob < KA)
                ? (const short*)A1 + (size_t)mrow[rt] * KA + kglob + quad * 8
                : (const short*)A2 + (size_t)mrow[rt] * KB + (kglob - KA) + quad * 8;
            f.v[rt] = *(const bf16x8*)ap;
        }
        return f;
    };

    f32x4 acc[2][8];
#pragma unroll
    for (int rt = 0; rt < 2; rt++)
#pragma unroll
        for (int nt = 0; nt < 8; nt++) acc[rt][nt] = {0.f, 0.f, 0.f, 0.f};

    AFrag a0f = loadA(0);
    AFrag a1f = loadA(32);

#pragma unroll
    for (int kt = 0; kt < KT; kt++) {
        int kg2 = kt * 32 + 64;                   // depth-2 prefetch target
        if (kg2 > K - 32) kg2 = K - 32;           // clamp (tail: dummy reload, valid addr)
        AFrag a_next = loadA(kg2);
#pragma unroll
        for (int nt = 0; nt < 8; nt++) {
            int nt_g = half * 8 + nt;
            bf16x8 b = *(const bf16x8*)(Wf + (size_t)((kt * 16 + nt_g) * 64 + lane) * 8);
#pragma unroll
            for (int rt = 0; rt < 2; rt++)
                acc[rt][nt] = __builtin_amdgcn_mfma_f32_16x16x32_bf16(a0f.v[rt], b, acc[rt][nt], 0, 0, 0);
        }
        a0f = a1f;
        a1f = a_next;
    }

    int isf32 = TOOUT ? *flag : 0;
    float* hf = TOOUT ? ((float*)dout + (size_t)M * 7) : nullptr;
    __hip_bfloat16* hb = TOOUT ? ((__hip_bfloat16*)dout + (size_t)M * 7) : outb;

#pragma unroll
    for (int rt = 0; rt < 2; rt++) {
#pragma unroll
        for (int nt = 0; nt < 8; nt++) {
            int col = cbase + nt * 16 + l15;
            float bv = bf2f(bias[col]);
#pragma unroll
            for (int r = 0; r < 4; r++) {
                int row = R0 + wave * 32 + rt * 16 + quad * 4 + r;
                if (row < M) {
                    float v = acc[rt][nt][r] + bv;
                    if (RELU) v = fmaxf(v, 0.f);
                    size_t idx = (size_t)row * 256 + col;
                    if (TOOUT && isf32) hf[idx] = v;
                    else                hb[idx] = __float2bfloat16(v);
                }
            }
        }
    }
}

// ---------------- heads: out1[N,4] @ d_out+0, out2[N,3] @ d_out+N*4; h2 from d_out (flag dtype)
__global__ void heads_kernel(const __hip_bfloat16* __restrict__ sb,
                             void* dout, int N, const int* __restrict__ flag) {
    int isf32 = *flag;
    int node = (blockIdx.x * blockDim.x + threadIdx.x) >> 6;
    int lane = threadIdx.x & 63;
    if (node >= N) return;
    float hv0, hv1, hv2, hv3;
    if (isf32) {
        const float4* hp = (const float4*)((const float*)dout + (size_t)N * 7);
        float4 v = hp[(size_t)node * 64 + lane];
        hv0 = v.x; hv1 = v.y; hv2 = v.z; hv3 = v.w;
    } else {
        const __hip_bfloat162* hp = (const __hip_bfloat162*)((const __hip_bfloat16*)dout + (size_t)N * 7);
        __hip_bfloat162 a = hp[(size_t)node * 128 + 2 * lane];
        __hip_bfloat162 b = hp[(size_t)node * 128 + 2 * lane + 1];
        hv0 = bf2f(a.x); hv1 = bf2f(a.y); hv2 = bf2f(b.x); hv3 = bf2f(b.y);
    }
#pragma unroll
    for (int r = 0; r < 7; r++) {
        const __hip_bfloat16* wrow = (r < 4) ? (sb + 512 + r * 256) : (sb + 1536 + (r - 4) * 256);
        const __hip_bfloat162* wr2 = (const __hip_bfloat162*)wrow;
        __hip_bfloat162 wa = wr2[2 * lane];
        __hip_bfloat162 wb = wr2[2 * lane + 1];
        float p = hv0 * bf2f(wa.x) + hv1 * bf2f(wa.y) + hv2 * bf2f(wb.x) + hv3 * bf2f(wb.y);
        for (int off = 32; off > 0; off >>= 1) p += __shfl_down(p, off, 64);
        if (lane == 0) {
            float bias = (r < 4) ? bf2f(sb[2304 + r]) : bf2f(sb[2308 + (r - 4)]);
            float v = p + bias;
            size_t idx = (r < 4) ? ((size_t)node * 4 + r)
                                 : ((size_t)N * 4 + (size_t)node * 3 + (r - 4));
            if (isf32) ((float*)dout)[idx] = v;
            else       ((__hip_bfloat16*)dout)[idx] = __float2bfloat16(v);
        }
    }
}

extern "C" void kernel_launch(void* const* d_in, const int* in_sizes, int n_in,
                              void* d_out, int out_size, void* d_ws, size_t ws_size,
                              hipStream_t stream) {
    const void* x   = d_in[0];
    const int*  ei  = (const int*)d_in[1];
    const void* W1l = d_in[2];
    const void* b1l = d_in[3];
    const void* W1r = d_in[4];
    const void* W2l = d_in[5];
    const void* b2l = d_in[6];
    const void* W2r = d_in[7];
    const void* Wh1 = d_in[8];
    const void* bh1 = d_in[9];
    const void* Wh2 = d_in[10];
    const void* bh2 = d_in[11];

    const int N = in_sizes[0] / 128;   // 50000
    const int E = in_sizes[1] / 2;     // 800000
    const int NB = (N + 1023) / 1024;  // scan blocks (49, <= 64 required by addC)

    // workspace layout (bytes), 64B-aligned; regions reused across phases:
    //   rank aliases h1 (rank dead before gemm1 writes h1)
    char* ws = (char*)d_ws;
    int*            offp   = (int*)(ws + 0);                   // (N+1)*4
    int*            deg    = (int*)(ws + 262144);              // N*4
    int*            bsum   = (int*)(ws + 524288);              // NB*4
    unsigned short* srcs   = (unsigned short*)(ws + 786432);   // E*2
    __hip_bfloat16* W1f    = (__hip_bfloat16*)(ws + 3986432);  // 65536*2 (frag order)
    __hip_bfloat16* W2f    = (__hip_bfloat16*)(ws + 4117504);  // 131072*2 (frag order)
    __hip_bfloat16* sb     = (__hip_bfloat16*)(ws + 4379648);  // 8KB
    __hip_bfloat16* xn     = (__hip_bfloat16*)(ws + 4387840);  // N*128*2
    __hip_bfloat16* h1     = (__hip_bfloat16*)(ws + 17187840); // N*256*2
    int*            rank   = (int*)(ws + 17187840);            // E*4 (aliases h1)
    __hip_bfloat16* agg    = (__hip_bfloat16*)(ws + 42787840); // N*256*2
    int*            flag   = (int*)(ws + 68387840);

    // zero deg, then fused pre-pass (detect + ingest + frag-order prep + deg/rank + flag)
    hipMemsetAsync(deg, 0, (size_t)N * 4, stream);
    pre_kernel<<<(N * 32 + 255) / 256, 256, 0, stream>>>(
        x, W1l, W1r, W2l, W2r, b1l, b2l, Wh1, Wh2, bh1, bh2, ei, E,
        xn, W1f, W2f, sb, deg, rank, flag, N);

    // CSR finalize; fill is atomic-free (uses rank from pre_kernel)
    scanA_kernel<<<NB, 256, 0, stream>>>(deg, offp, bsum, N);
    addC_kernel<<<(N + 255) / 256, 256, 0, stream>>>(offp, bsum, N, NB);
    fill_kernel<<<(E + 255) / 256, 256, 0, stream>>>(ei, E, offp, rank, srcs);

    const int rowBlks = (N + 127) / 128;   // 391

    // layer 1 (bf16): h1 = relu([agg1 | xn] @ W1^T + b1l)
    {
        int waves = (N + 3) / 4;
        gather1_kernel<<<(waves * 64 + 255) / 256, 256, 0, stream>>>(xn, offp, srcs, agg, N);
    }
    gemm_nolds<256, 128, true, false><<<rowBlks * 2, 256, 0, stream>>>(
        agg, xn, N, (const short*)W1f, sb, h1, nullptr, flag);

    // layer 2: h2 -> d_out h-region (flag dtype)
    {
        int waves = (N + 1) / 2;
        gather2_kernel<<<(waves * 64 + 255) / 256, 256, 0, stream>>>(h1, offp, srcs, agg, N);
    }
    gemm_nolds<512, 256, false, true><<<rowBlks * 2, 256, 0, stream>>>(
        agg, h1, N, (const short*)W2f, sb + 256, nullptr, d_out, flag);

    // heads -> out1/out2 (flag dtype), h2 read from d_out
    heads_kernel<<<(N + 3) / 4, 256, 0, stream>>>(sb, d_out, N, flag);
}

// Round 9
// 337.130 us; speedup vs baseline: 1.0675x; 1.0675x over previous
//
#include <hip/hip_runtime.h>
#include <hip/hip_bf16.h>

typedef short bf16x8 __attribute__((ext_vector_type(8)));   // 8 bf16 bit-patterns (4 VGPRs)
typedef float f32x4 __attribute__((ext_vector_type(4)));

__device__ __forceinline__ float bf2f(__hip_bfloat16 v) { return __bfloat162float(v); }
__device__ __forceinline__ float sh2f(short s) {
    union { float f; unsigned u; } c; c.u = ((unsigned)(unsigned short)s) << 16; return c.f;
}
__device__ __forceinline__ short f2sh(float f) {
    __hip_bfloat16 b = __float2bfloat16(f); return *(short*)&b;
}

__device__ __forceinline__ float loadAny(const void* p, size_t i, int isf32) {
    return isf32 ? ((const float*)p)[i] : bf2f(((const __hip_bfloat16*)p)[i]);
}

// ---------------- fused pre-pass: dtype detect (per-block, wave 0) + ingest x->bf16
//                  + weight prep (W1c | W2c | sb) + per-edge deg/rank atomics + flag
// deg must be zeroed (hipMemsetAsync) BEFORE this kernel.
__global__ void pre_kernel(const void* __restrict__ x,
                           const void* W1l, const void* W1r, const void* W2l, const void* W2r,
                           const void* b1l, const void* b2l, const void* Wh1, const void* Wh2,
                           const void* bh1, const void* bh2,
                           const int* __restrict__ ei, int E,
                           __hip_bfloat16* __restrict__ xn,
                           __hip_bfloat16* __restrict__ W1c, __hip_bfloat16* __restrict__ W2c,
                           __hip_bfloat16* __restrict__ sb,
                           int* __restrict__ deg, int* __restrict__ rank,
                           int* __restrict__ flag, int N) {
    __shared__ int sflag;
    int tid = threadIdx.x;
    if (tid < 64) {                               // wave 0: local dtype detect (128B of x)
        const unsigned short* xu = (const unsigned short*)x;
        unsigned short u = xu[tid * 2];
        unsigned e = (u >> 7) & 0xFF;
        bool good = (u == 0) || (e >= 110 && e <= 137);
        unsigned long long m = __ballot(good);
        if (tid == 0) sflag = (__popcll(m) < 32) ? 1 : 0;
    }
    __syncthreads();
    int isf32 = sflag;
    int gid = blockIdx.x * 256 + tid;
    if (gid == 0) *flag = isf32;                  // for gemm2 epilogue + heads

    if (gid < E) {                                // CSR pass 1: degree count + edge rank
        rank[gid] = atomicAdd(&deg[ei[E + gid]], 1);
    }

    int n4 = N * 32;
    if (gid < n4) {                               // ingest: 4 elems/thread
        short4 o;
        if (isf32) {
            float4 v = ((const float4*)x)[gid];
            o.x = f2sh(v.x); o.y = f2sh(v.y); o.z = f2sh(v.z); o.w = f2sh(v.w);
        } else {
            o = ((const short4*)x)[gid];
        }
        ((short4*)xn)[gid] = o;
    }

    if (gid < 65536) {                            // W1c = [W1l | W1r] rows of 256
        int n = gid >> 8, k = gid & 255;
        float v = (k < 128) ? loadAny(W1l, n * 128 + k, isf32)
                            : loadAny(W1r, n * 128 + (k - 128), isf32);
        W1c[gid] = __float2bfloat16(v);
        return;
    }
    int u = gid - 65536;
    if (u < 131072) {                             // W2c = [W2l | W2r] rows of 512
        int n = u >> 9, k = u & 511;
        float v = (k < 256) ? loadAny(W2l, n * 256 + k, isf32)
                            : loadAny(W2r, n * 256 + (k - 256), isf32);
        W2c[u] = __float2bfloat16(v);
        return;
    }
    int s = u - 131072;
    float v;
    if      (s < 256)  v = loadAny(b1l, s, isf32);
    else if (s < 512)  v = loadAny(b2l, s - 256, isf32);
    else if (s < 1536) v = loadAny(Wh1, s - 512, isf32);
    else if (s < 2304) v = loadAny(Wh2, s - 1536, isf32);
    else if (s < 2308) v = loadAny(bh1, s - 2304, isf32);
    else if (s < 2311) v = loadAny(bh2, s - 2308, isf32);
    else return;
    sb[s] = __float2bfloat16(v);
}

__global__ __launch_bounds__(256) void scanA_kernel(const int* __restrict__ deg,
                                                    int* __restrict__ off,
                                                    int* __restrict__ bsum, int N) {
    __shared__ int ts[256];
    int t = threadIdx.x;
    int base = blockIdx.x * 1024 + t * 4;
    int v0 = (base + 0 < N) ? deg[base + 0] : 0;
    int v1 = (base + 1 < N) ? deg[base + 1] : 0;
    int v2 = (base + 2 < N) ? deg[base + 2] : 0;
    int v3 = (base + 3 < N) ? deg[base + 3] : 0;
    int i0 = v0, i1 = i0 + v1, i2 = i1 + v2, i3 = i2 + v3;
    ts[t] = i3;
    __syncthreads();
    for (int d = 1; d < 256; d <<= 1) {
        int x = (t >= d) ? ts[t - d] : 0;
        __syncthreads();
        ts[t] += x;
        __syncthreads();
    }
    int excl = (t > 0) ? ts[t - 1] : 0;
    if (base + 0 < N) off[base + 1] = excl + i0;
    if (base + 1 < N) off[base + 2] = excl + i1;
    if (base + 2 < N) off[base + 3] = excl + i2;
    if (base + 3 < N) off[base + 4] = excl + i3;
    if (t == 255) bsum[blockIdx.x] = ts[255];
}

// addC with inline scan of bsum (nb <= 64): each block redundantly prefix-scans the
// 49 block totals in wave 0 (shfl_up), then applies the exclusive offset.
__global__ void addC_kernel(int* __restrict__ off, const int* __restrict__ bsum,
                            int N, int nb) {
    __shared__ int ex[64];
    int t = threadIdx.x;
    if (t < 64) {
        int v = (t < nb) ? bsum[t] : 0;
        for (int d = 1; d < 64; d <<= 1) {
            int y = __shfl_up(v, d, 64);
            if (t >= d) v += y;
        }
        ex[t] = v;                                // inclusive scan
    }
    __syncthreads();
    int i = blockIdx.x * 256 + t;
    if (i == 0) off[0] = 0;
    if (i < N) {
        int b = i >> 10;
        int excl = (b > 0) ? ex[b - 1] : 0;
        off[i + 1] += excl;
    }
}

// fill: NO atomics — pos = off[dst] + rank[t]; srcs stored as u16 (N < 65536)
__global__ void fill_kernel(const int* __restrict__ ei, int E,
                            const int* __restrict__ off, const int* __restrict__ rank,
                            unsigned short* __restrict__ srcs) {
    int t = blockIdx.x * blockDim.x + threadIdx.x;
    if (t >= E) return;
    int dst = ei[E + t];
    int pos = off[dst] + rank[t];
    srcs[pos] = (unsigned short)ei[t];
}

// ---------------- gather-mean F=128: 4 nodes/wave (16 lanes x 16B = 256B row), 8-way unroll
__global__ void gather1_kernel(const __hip_bfloat16* __restrict__ x,
                               const int* __restrict__ off,
                               const unsigned short* __restrict__ srcs,
                               __hip_bfloat16* __restrict__ agg, int N) {
    int gid  = blockIdx.x * blockDim.x + threadIdx.x;
    int wid  = gid >> 6;
    int lane = threadIdx.x & 63;
    int node = wid * 4 + (lane >> 4);
    int t    = lane & 15;                         // 16B unit within row (16 units)
    if (node >= N) return;
    int beg = off[node], end = off[node + 1];
    float a[8] = {0.f, 0.f, 0.f, 0.f, 0.f, 0.f, 0.f, 0.f};
    const bf16x8* xb = (const bf16x8*)x;
    int e = beg;
    for (; e + 7 < end; e += 8) {
        bf16x8 v[8];
#pragma unroll
        for (int j = 0; j < 8; j++) v[j] = xb[(size_t)srcs[e + j] * 16 + t];
#pragma unroll
        for (int j = 0; j < 8; j++)
#pragma unroll
            for (int k = 0; k < 8; k++) a[k] += sh2f(v[j][k]);
    }
    for (; e < end; e++) {
        bf16x8 v = xb[(size_t)srcs[e] * 16 + t];
#pragma unroll
        for (int k = 0; k < 8; k++) a[k] += sh2f(v[k]);
    }
    float inv = 1.0f / fmaxf((float)(end - beg), 1.0f);
    bf16x8 o;
#pragma unroll
    for (int k = 0; k < 8; k++) o[k] = f2sh(a[k] * inv);
    ((bf16x8*)agg)[(size_t)node * 16 + t] = o;
}

// ---------------- gather-mean F=256: 2 nodes/wave (32 lanes x 16B = 512B row), 8-way unroll
__global__ void gather2_kernel(const __hip_bfloat16* __restrict__ h,
                               const int* __restrict__ off,
                               const unsigned short* __restrict__ srcs,
                               __hip_bfloat16* __restrict__ agg, int N) {
    int gid  = blockIdx.x * blockDim.x + threadIdx.x;
    int wid  = gid >> 6;
    int lane = threadIdx.x & 63;
    int node = wid * 2 + (lane >> 5);
    int t    = lane & 31;                         // 16B unit within row (32 units)
    if (node >= N) return;
    int beg = off[node], end = off[node + 1];
    float a[8] = {0.f, 0.f, 0.f, 0.f, 0.f, 0.f, 0.f, 0.f};
    const bf16x8* hb = (const bf16x8*)h;
    int e = beg;
    for (; e + 7 < end; e += 8) {
        bf16x8 v[8];
#pragma unroll
        for (int j = 0; j < 8; j++) v[j] = hb[(size_t)srcs[e + j] * 32 + t];
#pragma unroll
        for (int j = 0; j < 8; j++)
#pragma unroll
            for (int k = 0; k < 8; k++) a[k] += sh2f(v[j][k]);
    }
    for (; e < end; e++) {
        bf16x8 v = hb[(size_t)srcs[e] * 32 + t];
#pragma unroll
        for (int k = 0; k < 8; k++) a[k] += sh2f(v[k]);
    }
    float inv = 1.0f / fmaxf((float)(end - beg), 1.0f);
    bf16x8 o;
#pragma unroll
    for (int k = 0; k < 8; k++) o[k] = f2sh(a[k] * inv);
    ((bf16x8*)agg)[(size_t)node * 32 + t] = o;
}

// ---------------- LDS-staged GEMM, software-pipelined (W chunk prefetch + depth-2 A prefetch)
// Tile: 128 rows x 128 cols per block, 4 waves (each wave 32 rows x 128 cols).
// W chunk in LDS: 128 cols x 128 k = 32 KB -> up to 5 blocks/CU; grid 2*ceil(M/128).
struct AFrag { bf16x8 v[2]; };

template <int K, int KA, bool RELU, bool TOOUT>
__global__ __launch_bounds__(256) void gemm_lds(const __hip_bfloat16* __restrict__ A1,
                                                const __hip_bfloat16* __restrict__ A2, int M,
                                                const __hip_bfloat16* __restrict__ W,
                                                const __hip_bfloat16* __restrict__ bias,
                                                __hip_bfloat16* __restrict__ outb,
                                                void* __restrict__ dout,
                                                const int* __restrict__ flag) {
    __shared__ short wlds[16384];                 // 32 KB: one 128(col)x128(k) W chunk
    constexpr int KB = K - KA;
    constexpr int NCHUNK = K / 128;
    int tid  = threadIdx.x;
    int wave = tid >> 6, lane = tid & 63, quad = lane >> 4, l15 = lane & 15;
    int rowBlk = blockIdx.x >> 1, half = blockIdx.x & 1;
    int R0 = rowBlk * 128;
    int cbase = half * 128;

    int mrow[2];
#pragma unroll
    for (int rt = 0; rt < 2; rt++) mrow[rt] = min(R0 + wave * 32 + rt * 16 + l15, M - 1);

    const short* Ws = (const short*)W;

    auto loadW = [&](int p, bf16x8* wreg) {
#pragma unroll
        for (int i = 0; i < 8; i++) {
            int unit = tid + i * 256;             // 0..2047
            int ln = unit & 63, nt = (unit >> 6) & 7, kt = unit >> 9;  // kt 0..3
            int row = cbase + nt * 16 + (ln & 15);
            int kk  = p * 128 + kt * 32 + (ln >> 4) * 8;
            wreg[i] = *(const bf16x8*)(Ws + (size_t)row * K + kk);
        }
    };
    auto storeW = [&](const bf16x8* wreg) {
#pragma unroll
        for (int i = 0; i < 8; i++) {
            int unit = tid + i * 256;
            *(bf16x8*)&wlds[unit * 8] = wreg[i];
        }
    };
    auto loadA = [&](int kglob) {
        AFrag f;
#pragma unroll
        for (int rt = 0; rt < 2; rt++) {
            const short* ap = (kglob < KA)
                ? (const short*)A1 + (size_t)mrow[rt] * KA + kglob + quad * 8
                : (const short*)A2 + (size_t)mrow[rt] * KB + (kglob - KA) + quad * 8;
            f.v[rt] = *(const bf16x8*)ap;
        }
        return f;
    };

    f32x4 acc[2][8];
#pragma unroll
    for (int rt = 0; rt < 2; rt++)
#pragma unroll
        for (int nt = 0; nt < 8; nt++) acc[rt][nt] = {0.f, 0.f, 0.f, 0.f};

    bf16x8 wreg[8];
    loadW(0, wreg);
    storeW(wreg);
    __syncthreads();
    AFrag a0f = loadA(0);
    AFrag a1f = loadA(32 < K ? 32 : 0);

    for (int p = 0; p < NCHUNK; p++) {
        if (p + 1 < NCHUNK) loadW(p + 1, wreg);   // global->reg prefetch, no LDS hazard
#pragma unroll
        for (int kt = 0; kt < 4; kt++) {
            int kg = p * 128 + kt * 32;
            int kg2 = kg + 64;                    // depth-2 prefetch target
            if (kg2 > K - 32) kg2 = K - 32;       // clamp (tail: dummy reload, valid addr)
            AFrag a_next = loadA(kg2);
#pragma unroll
            for (int nt = 0; nt < 8; nt++) {
                bf16x8 b = *(const bf16x8*)&wlds[((kt * 8 + nt) * 64 + lane) * 8];
#pragma unroll
                for (int rt = 0; rt < 2; rt++)
                    acc[rt][nt] = __builtin_amdgcn_mfma_f32_16x16x32_bf16(a0f.v[rt], b, acc[rt][nt], 0, 0, 0);
            }
            a0f = a1f;
            a1f = a_next;
        }
        if (p + 1 < NCHUNK) {
            __syncthreads();          // all waves done reading chunk p
            storeW(wreg);
            __syncthreads();
        }
    }

    int isf32 = TOOUT ? *flag : 0;
    float* hf = TOOUT ? ((float*)dout + (size_t)M * 7) : nullptr;
    __hip_bfloat16* hb = TOOUT ? ((__hip_bfloat16*)dout + (size_t)M * 7) : outb;

#pragma unroll
    for (int rt = 0; rt < 2; rt++) {
#pragma unroll
        for (int nt = 0; nt < 8; nt++) {
            int col = cbase + nt * 16 + l15;
            float bv = bf2f(bias[col]);
#pragma unroll
            for (int r = 0; r < 4; r++) {
                int row = R0 + wave * 32 + rt * 16 + quad * 4 + r;
                if (row < M) {
                    float v = acc[rt][nt][r] + bv;
                    if (RELU) v = fmaxf(v, 0.f);
                    size_t idx = (size_t)row * 256 + col;
                    if (TOOUT && isf32) hf[idx] = v;
                    else                hb[idx] = __float2bfloat16(v);
                }
            }
        }
    }
}

// ---------------- heads: out1[N,4] @ d_out+0, out2[N,3] @ d_out+N*4; h2 from d_out (flag dtype)
__global__ void heads_kernel(const __hip_bfloat16* __restrict__ sb,
                             void* dout, int N, const int* __restrict__ flag) {
    int isf32 = *flag;
    int node = (blockIdx.x * blockDim.x + threadIdx.x) >> 6;
    int lane = threadIdx.x & 63;
    if (node >= N) return;
    float hv0, hv1, hv2, hv3;
    if (isf32) {
        const float4* hp = (const float4*)((const float*)dout + (size_t)N * 7);
        float4 v = hp[(size_t)node * 64 + lane];
        hv0 = v.x; hv1 = v.y; hv2 = v.z; hv3 = v.w;
    } else {
        const __hip_bfloat162* hp = (const __hip_bfloat162*)((const __hip_bfloat16*)dout + (size_t)N * 7);
        __hip_bfloat162 a = hp[(size_t)node * 128 + 2 * lane];
        __hip_bfloat162 b = hp[(size_t)node * 128 + 2 * lane + 1];
        hv0 = bf2f(a.x); hv1 = bf2f(a.y); hv2 = bf2f(b.x); hv3 = bf2f(b.y);
    }
#pragma unroll
    for (int r = 0; r < 7; r++) {
        const __hip_bfloat16* wrow = (r < 4) ? (sb + 512 + r * 256) : (sb + 1536 + (r - 4) * 256);
        const __hip_bfloat162* wr2 = (const __hip_bfloat162*)wrow;
        __hip_bfloat162 wa = wr2[2 * lane];
        __hip_bfloat162 wb = wr2[2 * lane + 1];
        float p = hv0 * bf2f(wa.x) + hv1 * bf2f(wa.y) + hv2 * bf2f(wb.x) + hv3 * bf2f(wb.y);
        for (int off = 32; off > 0; off >>= 1) p += __shfl_down(p, off, 64);
        if (lane == 0) {
            float bias = (r < 4) ? bf2f(sb[2304 + r]) : bf2f(sb[2308 + (r - 4)]);
            float v = p + bias;
            size_t idx = (r < 4) ? ((size_t)node * 4 + r)
                                 : ((size_t)N * 4 + (size_t)node * 3 + (r - 4));
            if (isf32) ((float*)dout)[idx] = v;
            else       ((__hip_bfloat16*)dout)[idx] = __float2bfloat16(v);
        }
    }
}

extern "C" void kernel_launch(void* const* d_in, const int* in_sizes, int n_in,
                              void* d_out, int out_size, void* d_ws, size_t ws_size,
                              hipStream_t stream) {
    const void* x   = d_in[0];
    const int*  ei  = (const int*)d_in[1];
    const void* W1l = d_in[2];
    const void* b1l = d_in[3];
    const void* W1r = d_in[4];
    const void* W2l = d_in[5];
    const void* b2l = d_in[6];
    const void* W2r = d_in[7];
    const void* Wh1 = d_in[8];
    const void* bh1 = d_in[9];
    const void* Wh2 = d_in[10];
    const void* bh2 = d_in[11];

    const int N = in_sizes[0] / 128;   // 50000
    const int E = in_sizes[1] / 2;     // 800000
    const int NB = (N + 1023) / 1024;  // scan blocks (49, <= 64 required by addC)

    // workspace layout (bytes), 64B-aligned; regions reused across phases:
    //   rank aliases h1 (rank dead before gemm1 writes h1)
    char* ws = (char*)d_ws;
    int*            offp   = (int*)(ws + 0);                   // (N+1)*4
    int*            deg    = (int*)(ws + 262144);              // N*4
    int*            bsum   = (int*)(ws + 524288);              // NB*4
    unsigned short* srcs   = (unsigned short*)(ws + 786432);   // E*2
    __hip_bfloat16* W1c    = (__hip_bfloat16*)(ws + 3986432);  // 256*256*2
    __hip_bfloat16* W2c    = (__hip_bfloat16*)(ws + 4117504);  // 256*512*2
    __hip_bfloat16* sb     = (__hip_bfloat16*)(ws + 4379648);  // 8KB
    __hip_bfloat16* xn     = (__hip_bfloat16*)(ws + 4387840);  // N*128*2
    __hip_bfloat16* h1     = (__hip_bfloat16*)(ws + 17187840); // N*256*2
    int*            rank   = (int*)(ws + 17187840);            // E*4 (aliases h1)
    __hip_bfloat16* agg    = (__hip_bfloat16*)(ws + 42787840); // N*256*2
    int*            flag   = (int*)(ws + 68387840);

    // zero deg, then fused pre-pass (detect + ingest + prep + deg/rank atomics + flag)
    hipMemsetAsync(deg, 0, (size_t)N * 4, stream);
    pre_kernel<<<(N * 32 + 255) / 256, 256, 0, stream>>>(
        x, W1l, W1r, W2l, W2r, b1l, b2l, Wh1, Wh2, bh1, bh2, ei, E,
        xn, W1c, W2c, sb, deg, rank, flag, N);

    // CSR finalize; fill is atomic-free (uses rank from pre_kernel)
    scanA_kernel<<<NB, 256, 0, stream>>>(deg, offp, bsum, N);
    addC_kernel<<<(N + 255) / 256, 256, 0, stream>>>(offp, bsum, N, NB);
    fill_kernel<<<(E + 255) / 256, 256, 0, stream>>>(ei, E, offp, rank, srcs);

    const int rowBlks = (N + 127) / 128;   // 391

    // layer 1 (bf16): h1 = relu([agg1 | xn] @ W1c^T + b1l)
    {
        int waves = (N + 3) / 4;
        gather1_kernel<<<(waves * 64 + 255) / 256, 256, 0, stream>>>(xn, offp, srcs, agg, N);
    }
    gemm_lds<256, 128, true, false><<<rowBlks * 2, 256, 0, stream>>>(
        agg, xn, N, W1c, sb, h1, nullptr, flag);

    // layer 2: h2 -> d_out h-region (flag dtype)
    {
        int waves = (N + 1) / 2;
        gather2_kernel<<<(waves * 64 + 255) / 256, 256, 0, stream>>>(h1, offp, srcs, agg, N);
    }
    gemm_lds<512, 256, false, true><<<rowBlks * 2, 256, 0, stream>>>(
        agg, h1, N, W2c, sb + 256, nullptr, d_out, flag);

    // heads -> out1/out2 (flag dtype), h2 read from d_out
    heads_kernel<<<(N + 3) / 4, 256, 0, stream>>>(sb, d_out, N, flag);
}